// Round 1
// baseline (2503.358 us; speedup 1.0000x reference)
//
#include <hip/hip_runtime.h>
#include <math.h>

#define BATCH 8
#define SEQ   2048
#define DM    256
#define DQK   128
#define NHEADS 8
#define NK    16
#define DFF   1024

// ---------------------------------------------------------------------------
// Kernel A: per-token projections.
//  qn = l2norm(x@Wq+bq), kn = l2norm(x@Wk+bk), knsq = sum(kn^2) (numeric),
//  vall = (LN(x; g1,b1)) @ Wv + bv      [LN(x_v)=LN(x)[idx] since LN is row-wise]
// 8 tokens/block so Wq/Wk/Wv stream once per block (weights: 512KB/block).
// ---------------------------------------------------------------------------
__global__ __launch_bounds__(256) void proj_kernel(
    const float* __restrict__ x,
    const float* __restrict__ Wq, const float* __restrict__ bq,
    const float* __restrict__ Wk, const float* __restrict__ bk,
    const float* __restrict__ Wv, const float* __restrict__ bv,
    const float* __restrict__ g1, const float* __restrict__ b1,
    float* __restrict__ qn, float* __restrict__ kn,
    float* __restrict__ knsq, float* __restrict__ vall)
{
    __shared__ __align__(16) float xs[8 * 256];
    __shared__ __align__(16) float xn[8 * 256];
    __shared__ float stat_m[8], stat_r[8];
    __shared__ float nred[8][2], kred[8][2], k2red[8][2];

    const int tid = threadIdx.x;
    const size_t t0 = (size_t)blockIdx.x * 8;

    for (int i = tid; i < 8 * 256; i += 256) xs[i] = x[t0 * DM + i];
    __syncthreads();

    // LayerNorm stats per token: 32 lanes per token (group aligned within wave)
    {
        int tok = tid >> 5, l = tid & 31;
        float s = 0.f, s2 = 0.f;
        #pragma unroll
        for (int i = 0; i < 8; ++i) {
            float v = xs[tok * 256 + l + 32 * i];
            s += v; s2 += v * v;
        }
        #pragma unroll
        for (int m = 1; m < 32; m <<= 1) { s += __shfl_xor(s, m); s2 += __shfl_xor(s2, m); }
        if (l == 0) {
            float mean = s * (1.f / 256.f);
            float var  = s2 * (1.f / 256.f) - mean * mean;
            stat_m[tok] = mean;
            stat_r[tok] = rsqrtf(var + 1e-5f);
        }
    }
    __syncthreads();
    for (int i = tid; i < 8 * 256; i += 256) {
        int tok = i >> 8, d = i & 255;
        xn[i] = (xs[i] - stat_m[tok]) * stat_r[tok] * g1[d] + b1[d];
    }
    __syncthreads();

    // q/k projection: thread owns column (tid&127) for 4 tokens (half = tid>>7)
    {
        const int col = tid & 127, half = tid >> 7;
        float qa[4] = {0.f, 0.f, 0.f, 0.f}, ka[4] = {0.f, 0.f, 0.f, 0.f};
        for (int d = 0; d < 256; ++d) {
            float wq = Wq[d * DQK + col];
            float wk = Wk[d * DQK + col];
            #pragma unroll
            for (int t = 0; t < 4; ++t) {
                float xv = xs[(half * 4 + t) * 256 + d];   // LDS broadcast
                qa[t] = fmaf(xv, wq, qa[t]);
                ka[t] = fmaf(xv, wk, ka[t]);
            }
        }
        #pragma unroll
        for (int t = 0; t < 4; ++t) { qa[t] += bq[col]; ka[t] += bk[col]; }

        // L2 norms: each token's 128 cols span 2 waves -> shfl + LDS combine
        const int sub = (tid >> 6) & 1;
        #pragma unroll
        for (int t = 0; t < 4; ++t) {
            float sq = qa[t] * qa[t], sk = ka[t] * ka[t];
            #pragma unroll
            for (int m = 1; m < 64; m <<= 1) { sq += __shfl_xor(sq, m); sk += __shfl_xor(sk, m); }
            if ((tid & 63) == 0) { nred[half * 4 + t][sub] = sq; kred[half * 4 + t][sub] = sk; }
        }
        __syncthreads();
        float kvv[4];
        #pragma unroll
        for (int t = 0; t < 4; ++t) {
            int tok = half * 4 + t;
            float nq = sqrtf(nred[tok][0] + nred[tok][1]);
            float nk = sqrtf(kred[tok][0] + kred[tok][1]);
            float qv = qa[t] / fmaxf(nq, 1e-12f);
            float kv = ka[t] / fmaxf(nk, 1e-12f);
            qn[(t0 + tok) * DQK + col] = qv;
            kn[(t0 + tok) * DQK + col] = kv;
            kvv[t] = kv;
        }
        // numeric sum(kn^2) to mirror the reference's d2 term
        #pragma unroll
        for (int t = 0; t < 4; ++t) {
            float s2 = kvv[t] * kvv[t];
            #pragma unroll
            for (int m = 1; m < 64; m <<= 1) s2 += __shfl_xor(s2, m);
            if ((tid & 63) == 0) k2red[half * 4 + t][sub] = s2;
        }
        __syncthreads();
        if (tid < 8) knsq[t0 + tid] = k2red[tid][0] + k2red[tid][1];
    }

    // v projection: thread owns output col tid for all 8 tokens
    {
        float va[8] = {0.f, 0.f, 0.f, 0.f, 0.f, 0.f, 0.f, 0.f};
        for (int d = 0; d < 256; ++d) {
            float w = Wv[d * DM + tid];
            #pragma unroll
            for (int t = 0; t < 8; ++t) va[t] = fmaf(xn[t * 256 + d], w, va[t]);
        }
        float bvv = bv[tid];
        #pragma unroll
        for (int t = 0; t < 8; ++t) vall[(t0 + t) * DM + tid] = va[t] + bvv;
    }
}

// ---------------------------------------------------------------------------
// Kernel B: per-query scores (2*qn.kn - knsq), exact top-16, windowed MHA,
// Wo projection, first residual -> writes x_new to d_out.
// 4 queries per block (one wave per query). LDS: 32KB scores + padded tiles.
// ---------------------------------------------------------------------------
__global__ __launch_bounds__(256) void attn_kernel(
    const float* __restrict__ x,
    const float* __restrict__ qn_g, const float* __restrict__ kn_g,
    const float* __restrict__ knsq_g, const float* __restrict__ vall,
    const float* __restrict__ Wo, const float* __restrict__ bo,
    const float* __restrict__ rw, float* __restrict__ out)
{
    __shared__ __align__(16) float s_ld[4 * SEQ];      // 32 KB
    __shared__ __align__(16) float qn_ld[4 * DQK];     // 2 KB
    __shared__ __align__(16) float kn_s[NK * 129];     // padded (129: bank-free)
    __shared__ __align__(16) float v_s[NK * 257];      // padded (257: bank-free)
    __shared__ float attn_ld[NHEADS * NK];
    __shared__ __align__(16) float o4[4 * DM];
    __shared__ int topidx[4 * NK];

    const int tid = threadIdx.x;
    const int bb = blockIdx.x >> 9;            // 512 blocks per batch
    const int n0 = (blockIdx.x & 511) * 4;
    const size_t tq0 = (size_t)bb * SEQ + n0;

    for (int i = tid; i < 4 * DQK; i += 256) qn_ld[i] = qn_g[tq0 * DQK + i];
    __syncthreads();

    // phase 1: scores. wave = query, lane strides over keys.
    {
        const int q = tid >> 6, lane = tid & 63;
        const float* qrow = qn_ld + q * DQK;
        const float* knb = kn_g + (size_t)bb * SEQ * DQK;
        const float* ksq = knsq_g + (size_t)bb * SEQ;
        for (int i = 0; i < 32; ++i) {
            int j = lane + 64 * i;
            const float* krow = knb + (size_t)j * DQK;
            float acc = 0.f;
            #pragma unroll 8
            for (int d = 0; d < DQK; d += 4) {
                float4 kv = *(const float4*)(krow + d);
                float4 qv = *(const float4*)(qrow + d);
                acc = fmaf(qv.x, kv.x, acc);
                acc = fmaf(qv.y, kv.y, acc);
                acc = fmaf(qv.z, kv.z, acc);
                acc = fmaf(qv.w, kv.w, acc);
            }
            s_ld[q * SEQ + j] = 2.f * acc - ksq[j];   // rank key: larger == closer
        }
    }
    __syncthreads();

    // phase 2: exact top-16 per query, lowest-index tiebreak (matches lax.top_k set)
    {
        const int q = tid >> 6, lane = tid & 63;
        float* srow = s_ld + q * SEQ;
        for (int r = 0; r < NK; ++r) {
            float bvv = -INFINITY; int bi = 0x7fffffff;
            for (int i = 0; i < 32; ++i) {
                int j = lane + 64 * i;
                float v = srow[j];
                if (v > bvv || (v == bvv && j < bi)) { bvv = v; bi = j; }
            }
            #pragma unroll
            for (int m = 1; m < 64; m <<= 1) {
                float ov = __shfl_xor(bvv, m);
                int   oi = __shfl_xor(bi, m);
                if (ov > bvv || (ov == bvv && oi < bi)) { bvv = ov; bi = oi; }
            }
            if (lane == 0) { topidx[q * NK + r] = bi; srow[bi] = -INFINITY; }
            __syncthreads();   // uniform: makes lane0's LDS write visible to all
        }
    }

    // phase 3a: per query: gather neighbors, logits, softmax, P@V -> o4
    for (int q = 0; q < 4; ++q) {
        const int* idxq = topidx + q * NK;
        const float* knb = kn_g + (size_t)bb * SEQ * DQK;
        for (int i = tid; i < NK * DQK; i += 256) {
            int row = i >> 7, d = i & 127;
            kn_s[row * 129 + d] = knb[(size_t)idxq[row] * DQK + d];
        }
        for (int i = tid; i < NK * DM; i += 256) {
            int row = i >> 8, d = i & 255;
            v_s[row * 257 + d] = vall[((size_t)bb * SEQ + idxq[row]) * DM + d];
        }
        __syncthreads();
        if (tid < NHEADS * NK) {
            int h = tid >> 4, kk = tid & 15;
            float lg = 0.f;
            #pragma unroll
            for (int d = 0; d < 16; ++d)
                lg = fmaf(qn_ld[q * DQK + h * 16 + d], kn_s[kk * 129 + h * 16 + d], lg);
            lg *= 0.25f;                                  // 1/sqrt(dh=16)
            float mx = lg;
            #pragma unroll
            for (int m = 1; m < 16; m <<= 1) mx = fmaxf(mx, __shfl_xor(mx, m));
            float e = expf(lg - mx);
            float ssum = e;
            #pragma unroll
            for (int m = 1; m < 16; m <<= 1) ssum += __shfl_xor(ssum, m);
            attn_ld[h * NK + kk] = e / ssum;
        }
        __syncthreads();
        {
            int h = tid >> 5;                              // dv=32: out dim tid -> head tid>>5
            float o = 0.f;
            #pragma unroll
            for (int k = 0; k < NK; ++k)
                o = fmaf(attn_ld[h * NK + k], v_s[k * 257 + tid], o);
            o4[q * DM + tid] = o;
        }
        __syncthreads();
    }

    // phase 3b: Wo streamed once for all 4 queries, + bias, residual
    {
        float acc[4] = {0.f, 0.f, 0.f, 0.f};
        for (int d = 0; d < DM; ++d) {
            float w = Wo[d * DM + tid];
            #pragma unroll
            for (int q = 0; q < 4; ++q) acc[q] = fmaf(o4[q * DM + d], w, acc[q]);
        }
        float bov = bo[tid];
        float rwv = rw[0];
        #pragma unroll
        for (int q = 0; q < 4; ++q) {
            size_t t = tq0 + q;
            out[t * DM + tid] = x[t * DM + tid] + (acc[q] + bov) * rwv;
        }
    }
}

// ---------------------------------------------------------------------------
// Kernel C: FFN. Reads x_new from d_out, writes final output in place.
// 8 tokens/block so W1/W2 (1MB each... 2MB total per 8 tokens) stream once.
// ---------------------------------------------------------------------------
__global__ __launch_bounds__(256) void ffn_kernel(
    float* __restrict__ io,
    const float* __restrict__ gf, const float* __restrict__ bf,
    const float* __restrict__ W1, const float* __restrict__ b1f,
    const float* __restrict__ W2, const float* __restrict__ b2f,
    const float* __restrict__ rw)
{
    __shared__ __align__(16) float xs[8 * 256];
    __shared__ __align__(16) float xn[8 * 256];
    __shared__ __align__(16) float hg[8 * 1024];   // gelu(h), 32 KB
    __shared__ float stat_m[8], stat_r[8];

    const int tid = threadIdx.x;
    const size_t t0 = (size_t)blockIdx.x * 8;

    for (int i = tid; i < 8 * 256; i += 256) xs[i] = io[t0 * DM + i];
    __syncthreads();
    {
        int tok = tid >> 5, l = tid & 31;
        float s = 0.f, s2 = 0.f;
        #pragma unroll
        for (int i = 0; i < 8; ++i) {
            float v = xs[tok * 256 + l + 32 * i];
            s += v; s2 += v * v;
        }
        #pragma unroll
        for (int m = 1; m < 32; m <<= 1) { s += __shfl_xor(s, m); s2 += __shfl_xor(s2, m); }
        if (l == 0) {
            float mean = s * (1.f / 256.f);
            float var  = s2 * (1.f / 256.f) - mean * mean;
            stat_m[tok] = mean;
            stat_r[tok] = rsqrtf(var + 1e-5f);
        }
    }
    __syncthreads();
    for (int i = tid; i < 8 * 256; i += 256) {
        int tok = i >> 8, d = i & 255;
        xn[i] = (xs[i] - stat_m[tok]) * stat_r[tok] * gf[d] + bf[d];
    }
    __syncthreads();

    // h = xn @ W1 + b1f ; gelu exact
    {
        float a[4][8];
        #pragma unroll
        for (int c = 0; c < 4; ++c)
            #pragma unroll
            for (int t = 0; t < 8; ++t) a[c][t] = 0.f;
        for (int d = 0; d < 256; ++d) {
            float xv[8];
            #pragma unroll
            for (int t = 0; t < 8; ++t) xv[t] = xn[t * 256 + d];
            #pragma unroll
            for (int c = 0; c < 4; ++c) {
                float w = W1[d * DFF + tid + 256 * c];
                #pragma unroll
                for (int t = 0; t < 8; ++t) a[c][t] = fmaf(xv[t], w, a[c][t]);
            }
        }
        #pragma unroll
        for (int c = 0; c < 4; ++c) {
            float bb1 = b1f[tid + 256 * c];
            #pragma unroll
            for (int t = 0; t < 8; ++t) {
                float h = a[c][t] + bb1;
                hg[t * 1024 + tid + 256 * c] = 0.5f * h * (1.f + erff(h * 0.70710678118654752f));
            }
        }
    }
    __syncthreads();

    // out = x_new + (gelu(h) @ W2 + b2f) * rw
    {
        float a2[8];
        #pragma unroll
        for (int t = 0; t < 8; ++t) a2[t] = 0.f;
        for (int i = 0; i < 1024; i += 4) {
            float w0 = W2[(i + 0) * DM + tid];
            float w1 = W2[(i + 1) * DM + tid];
            float w2 = W2[(i + 2) * DM + tid];
            float w3 = W2[(i + 3) * DM + tid];
            #pragma unroll
            for (int t = 0; t < 8; ++t) {
                float4 hv = *(const float4*)(hg + t * 1024 + i);   // b128 broadcast
                a2[t] = fmaf(hv.x, w0, a2[t]);
                a2[t] = fmaf(hv.y, w1, a2[t]);
                a2[t] = fmaf(hv.z, w2, a2[t]);
                a2[t] = fmaf(hv.w, w3, a2[t]);
            }
        }
        float rwv = rw[0];
        float b2v = b2f[tid];
        #pragma unroll
        for (int t = 0; t < 8; ++t)
            io[(t0 + t) * DM + tid] = xs[t * 256 + tid] + (a2[t] + b2v) * rwv;
    }
}

// ---------------------------------------------------------------------------
extern "C" void kernel_launch(void* const* d_in, const int* in_sizes, int n_in,
                              void* d_out, int out_size, void* d_ws, size_t ws_size,
                              hipStream_t stream)
{
    const float* x   = (const float*)d_in[0];
    const float* Wq  = (const float*)d_in[1];
    const float* bq  = (const float*)d_in[2];
    const float* Wk  = (const float*)d_in[3];
    const float* bk  = (const float*)d_in[4];
    const float* Wv  = (const float*)d_in[5];
    const float* bv  = (const float*)d_in[6];
    const float* Wo  = (const float*)d_in[7];
    const float* bo  = (const float*)d_in[8];
    const float* g1  = (const float*)d_in[9];
    const float* b1  = (const float*)d_in[10];
    const float* gf  = (const float*)d_in[11];
    const float* bf  = (const float*)d_in[12];
    const float* W1  = (const float*)d_in[13];
    const float* b1f = (const float*)d_in[14];
    const float* W2  = (const float*)d_in[15];
    const float* b2f = (const float*)d_in[16];
    const float* rw  = (const float*)d_in[17];
    float* out = (float*)d_out;

    // workspace layout (33.6 MB total): qn | kn | vall | knsq
    float* ws   = (float*)d_ws;
    float* qn   = ws;
    float* kn   = qn + (size_t)BATCH * SEQ * DQK;
    float* vall = kn + (size_t)BATCH * SEQ * DQK;
    float* knsq = vall + (size_t)BATCH * SEQ * DM;

    proj_kernel<<<BATCH * SEQ / 8, 256, 0, stream>>>(x, Wq, bq, Wk, bk, Wv, bv, g1, b1,
                                                     qn, kn, knsq, vall);
    attn_kernel<<<BATCH * SEQ / 4, 256, 0, stream>>>(x, qn, kn, knsq, vall, Wo, bo, rw, out);
    ffn_kernel<<<BATCH * SEQ / 8, 256, 0, stream>>>(out, gf, bf, W1, b1f, W2, b2f, rw);
}

// Round 2
// 862.150 us; speedup vs baseline: 2.9036x; 2.9036x over previous
//
#include <hip/hip_runtime.h>
#include <math.h>

#define BATCH 8
#define SEQ   2048
#define DM    256
#define DQK   128
#define NHEADS 8
#define NK    16
#define DFF   1024

// ---------------------------------------------------------------------------
// Kernel A: per-token projections.
//  qn = l2norm(x@Wq+bq), kn = l2norm(x@Wk+bk), knT = kn transposed per batch,
//  knsq = sum(kn^2) (numeric), vall = LN(x;g1,b1) @ Wv + bv.
// blockIdx swizzled so batch == blockIdx&7 (XCD L2 affinity).
// ---------------------------------------------------------------------------
__global__ __launch_bounds__(256) void proj_kernel(
    const float* __restrict__ x,
    const float* __restrict__ Wq, const float* __restrict__ bq,
    const float* __restrict__ Wk, const float* __restrict__ bk,
    const float* __restrict__ Wv, const float* __restrict__ bv,
    const float* __restrict__ g1, const float* __restrict__ b1,
    float* __restrict__ qn, float* __restrict__ kn, float* __restrict__ knT,
    float* __restrict__ knsq, float* __restrict__ vall)
{
    __shared__ __align__(16) float xs[8 * 256];
    __shared__ __align__(16) float xn[8 * 256];
    __shared__ __align__(16) float ks[8 * 128];
    __shared__ float stat_m[8], stat_r[8];
    __shared__ float nred[8][2], kred[8][2], k2red[8][2];

    const int tid = threadIdx.x;
    const int b = blockIdx.x & 7;
    const int chunk = blockIdx.x >> 3;
    const size_t t0 = (size_t)b * SEQ + (size_t)chunk * 8;

    for (int i = tid; i < 8 * 256; i += 256) xs[i] = x[t0 * DM + i];
    __syncthreads();

    // LayerNorm stats per token: 32 lanes per token
    {
        int tok = tid >> 5, l = tid & 31;
        float s = 0.f, s2 = 0.f;
        #pragma unroll
        for (int i = 0; i < 8; ++i) {
            float v = xs[tok * 256 + l + 32 * i];
            s += v; s2 += v * v;
        }
        #pragma unroll
        for (int m = 1; m < 32; m <<= 1) { s += __shfl_xor(s, m); s2 += __shfl_xor(s2, m); }
        if (l == 0) {
            float mean = s * (1.f / 256.f);
            float var  = s2 * (1.f / 256.f) - mean * mean;
            stat_m[tok] = mean;
            stat_r[tok] = rsqrtf(var + 1e-5f);
        }
    }
    __syncthreads();
    for (int i = tid; i < 8 * 256; i += 256) {
        int tok = i >> 8, d = i & 255;
        xn[i] = (xs[i] - stat_m[tok]) * stat_r[tok] * g1[d] + b1[d];
    }
    __syncthreads();

    // q/k projection: thread owns column (tid&127) for 4 tokens (half = tid>>7)
    {
        const int col = tid & 127, half = tid >> 7;
        float qa[4] = {0.f, 0.f, 0.f, 0.f}, ka[4] = {0.f, 0.f, 0.f, 0.f};
        for (int d = 0; d < 256; ++d) {
            float wq = Wq[d * DQK + col];
            float wk = Wk[d * DQK + col];
            #pragma unroll
            for (int t = 0; t < 4; ++t) {
                float xv = xs[(half * 4 + t) * 256 + d];
                qa[t] = fmaf(xv, wq, qa[t]);
                ka[t] = fmaf(xv, wk, ka[t]);
            }
        }
        #pragma unroll
        for (int t = 0; t < 4; ++t) { qa[t] += bq[col]; ka[t] += bk[col]; }

        const int sub = (tid >> 6) & 1;
        #pragma unroll
        for (int t = 0; t < 4; ++t) {
            float sq = qa[t] * qa[t], sk = ka[t] * ka[t];
            #pragma unroll
            for (int m = 1; m < 64; m <<= 1) { sq += __shfl_xor(sq, m); sk += __shfl_xor(sk, m); }
            if ((tid & 63) == 0) { nred[half * 4 + t][sub] = sq; kred[half * 4 + t][sub] = sk; }
        }
        __syncthreads();
        float kvv[4];
        #pragma unroll
        for (int t = 0; t < 4; ++t) {
            int tok = half * 4 + t;
            float nq = sqrtf(nred[tok][0] + nred[tok][1]);
            float nk = sqrtf(kred[tok][0] + kred[tok][1]);
            float qv = qa[t] / fmaxf(nq, 1e-12f);
            float kv = ka[t] / fmaxf(nk, 1e-12f);
            qn[(t0 + tok) * DQK + col] = qv;
            kn[(t0 + tok) * DQK + col] = kv;
            ks[tok * 128 + col] = kv;
            kvv[t] = kv;
        }
        #pragma unroll
        for (int t = 0; t < 4; ++t) {
            float s2 = kvv[t] * kvv[t];
            #pragma unroll
            for (int m = 1; m < 64; m <<= 1) s2 += __shfl_xor(s2, m);
            if ((tid & 63) == 0) k2red[half * 4 + t][sub] = s2;
        }
        __syncthreads();
        if (tid < 8) knsq[t0 + tid] = k2red[tid][0] + k2red[tid][1];
    }

    // transpose-write knT[b][d][key]: thread (tid<128) owns dim tid, 8 tokens
    if (tid < 128) {
        float tmp[8];
        #pragma unroll
        for (int t = 0; t < 8; ++t) tmp[t] = ks[t * 128 + tid];
        float* dst = knT + ((size_t)b * DQK + tid) * SEQ + (size_t)chunk * 8;
        *(float4*)(dst)     = make_float4(tmp[0], tmp[1], tmp[2], tmp[3]);
        *(float4*)(dst + 4) = make_float4(tmp[4], tmp[5], tmp[6], tmp[7]);
    }

    // v projection: thread owns output col tid for all 8 tokens
    {
        float va[8] = {0.f, 0.f, 0.f, 0.f, 0.f, 0.f, 0.f, 0.f};
        for (int d = 0; d < 256; ++d) {
            float w = Wv[d * DM + tid];
            #pragma unroll
            for (int t = 0; t < 8; ++t) va[t] = fmaf(xn[t * 256 + d], w, va[t]);
        }
        float bvv = bv[tid];
        #pragma unroll
        for (int t = 0; t < 8; ++t) vall[(t0 + t) * DM + tid] = va[t] + bvv;
    }
}

// ---------------------------------------------------------------------------
// Kernel B: 8 queries/block. Phase 1: register-blocked score GEMM from knT
// (thread owns 8 keys, 64 fp32 accumulators, q broadcast from LDS).
// Phase 2: register-resident exact top-16 (2 passes of 4 queries, 32KB LDS).
// Phase 3: per-wave MHA (logits/softmax/PV) + shared Wo stream + residual.
// blockIdx swizzled so batch == blockIdx&7 keeps kn/knT/vall in one XCD L2.
// ---------------------------------------------------------------------------
__global__ __launch_bounds__(256, 2) void attn_kernel(
    const float* __restrict__ x,
    const float* __restrict__ qn_g, const float* __restrict__ kn_g,
    const float* __restrict__ knT, const float* __restrict__ knsq_g,
    const float* __restrict__ vall,
    const float* __restrict__ Wo, const float* __restrict__ bo,
    const float* __restrict__ rw, float* __restrict__ out)
{
    __shared__ __align__(16) float s_ld[4 * SEQ];     // 32 KB (score passes)
    __shared__ __align__(16) float qs[8 * DQK];       // 4 KB
    __shared__ __align__(16) float attn_s[8 * 128];   // 4 KB  [q][h][k]
    __shared__ __align__(16) float o8[8 * DM];        // 8 KB
    __shared__ int topidx[8 * NK];

    const int tid = threadIdx.x;
    const int lane = tid & 63, wave = tid >> 6;
    const int b = blockIdx.x & 7;
    const int chunk = blockIdx.x >> 3;
    const size_t tq0 = (size_t)b * SEQ + (size_t)chunk * 8;
    const size_t rowb = (size_t)b * SEQ;

    // stage 8 query vectors
    *(float4*)&qs[tid * 4] = *(const float4*)&qn_g[tq0 * DQK + tid * 4];
    __syncthreads();

    // ---- phase 1: scores. thread owns keys [8*tid .. 8*tid+7], all 8 queries.
    float acc[8][8];
    #pragma unroll
    for (int q = 0; q < 8; ++q)
        #pragma unroll
        for (int k = 0; k < 8; ++k) acc[q][k] = 0.f;

    const float* kTb = knT + (size_t)b * DQK * SEQ;
    const int key0 = tid * 8;
    for (int d = 0; d < DQK; d += 4) {
        float kv[4][8];
        #pragma unroll
        for (int dd = 0; dd < 4; ++dd) {
            *(float4*)&kv[dd][0] = *(const float4*)&kTb[(size_t)(d + dd) * SEQ + key0];
            *(float4*)&kv[dd][4] = *(const float4*)&kTb[(size_t)(d + dd) * SEQ + key0 + 4];
        }
        #pragma unroll
        for (int q = 0; q < 8; ++q) {
            float4 qv = *(const float4*)&qs[q * DQK + d];
            float qq[4] = {qv.x, qv.y, qv.z, qv.w};
            #pragma unroll
            for (int dd = 0; dd < 4; ++dd)
                #pragma unroll
                for (int k = 0; k < 8; ++k)
                    acc[q][k] = fmaf(qq[dd], kv[dd][k], acc[q][k]);
        }
    }

    float ksq[8];
    {
        const float* ksqb = knsq_g + rowb + key0;
        float4 a = *(const float4*)(ksqb);
        float4 c = *(const float4*)(ksqb + 4);
        ksq[0] = a.x; ksq[1] = a.y; ksq[2] = a.z; ksq[3] = a.w;
        ksq[4] = c.x; ksq[5] = c.y; ksq[6] = c.z; ksq[7] = c.w;
    }

    // ---- phase 2: exact top-16, two passes of 4 queries
    for (int p = 0; p < 2; ++p) {
        __syncthreads();   // previous pass scans done before overwrite
        #pragma unroll
        for (int qq = 0; qq < 4; ++qq) {
            int q = 4 * p + qq;
            #pragma unroll
            for (int j = 0; j < 8; ++j)
                s_ld[qq * SEQ + key0 + j] = 2.f * acc[q][j] - ksq[j];
        }
        __syncthreads();
        {
            // wave owns query 4*p + wave; candidates in registers
            float v[32];
            #pragma unroll
            for (int i = 0; i < 32; ++i) v[i] = s_ld[wave * SEQ + lane + 64 * i];
            const int qg = 4 * p + wave;
            for (int r = 0; r < NK; ++r) {
                float bv = v[0]; int bi = 0;
                #pragma unroll
                for (int i = 1; i < 32; ++i)
                    if (v[i] > bv) { bv = v[i]; bi = i; }   // strict: keeps smallest i
                int gi = lane + 64 * bi;
                #pragma unroll
                for (int m = 1; m < 64; m <<= 1) {
                    float ov = __shfl_xor(bv, m);
                    int   oi = __shfl_xor(gi, m);
                    if (ov > bv || (ov == bv && oi < gi)) { bv = ov; gi = oi; }
                }
                if (lane == (gi & 63)) {
                    int slot = gi >> 6;
                    #pragma unroll
                    for (int i = 0; i < 32; ++i)
                        if (slot == i) v[i] = -INFINITY;
                }
                if (lane == 0) topidx[qg * NK + r] = gi;
            }
        }
    }
    __syncthreads();

    // ---- phase 3a: per-wave MHA. wave handles queries wave and wave+4.
    for (int qq = 0; qq < 2; ++qq) {
        const int q = wave + 4 * qq;
        const int h = lane >> 3;
        const int k1 = lane & 7, k2 = 8 + (lane & 7);
        const int i1 = topidx[q * NK + k1], i2 = topidx[q * NK + k2];
        const float* kr1 = kn_g + (rowb + i1) * DQK + h * 16;
        const float* kr2 = kn_g + (rowb + i2) * DQK + h * 16;
        float lg1 = 0.f, lg2 = 0.f;
        #pragma unroll
        for (int d = 0; d < 16; d += 4) {
            float4 qv = *(const float4*)&qs[q * DQK + h * 16 + d];
            float4 a1 = *(const float4*)&kr1[d];
            float4 a2 = *(const float4*)&kr2[d];
            lg1 = fmaf(qv.x, a1.x, lg1); lg1 = fmaf(qv.y, a1.y, lg1);
            lg1 = fmaf(qv.z, a1.z, lg1); lg1 = fmaf(qv.w, a1.w, lg1);
            lg2 = fmaf(qv.x, a2.x, lg2); lg2 = fmaf(qv.y, a2.y, lg2);
            lg2 = fmaf(qv.z, a2.z, lg2); lg2 = fmaf(qv.w, a2.w, lg2);
        }
        lg1 *= 0.25f; lg2 *= 0.25f;                    // 1/sqrt(dh=16)
        float mx = fmaxf(lg1, lg2);
        #pragma unroll
        for (int m = 1; m < 8; m <<= 1) mx = fmaxf(mx, __shfl_xor(mx, m));
        float e1 = expf(lg1 - mx), e2 = expf(lg2 - mx);
        float ssum = e1 + e2;
        #pragma unroll
        for (int m = 1; m < 8; m <<= 1) ssum += __shfl_xor(ssum, m);
        attn_s[q * 128 + h * 16 + k1] = e1 / ssum;
        attn_s[q * 128 + h * 16 + k2] = e2 / ssum;
        __syncthreads();

        // PV: lane owns dims {lane, lane+64, lane+128, lane+192}
        float o[4] = {0.f, 0.f, 0.f, 0.f};
        for (int k = 0; k < NK; ++k) {
            const float* vr = vall + (rowb + topidx[q * NK + k]) * DM;
            #pragma unroll
            for (int j = 0; j < 4; ++j) {
                int d = lane + 64 * j;
                o[j] = fmaf(attn_s[q * 128 + (d >> 5) * 16 + k], vr[d], o[j]);
            }
        }
        #pragma unroll
        for (int j = 0; j < 4; ++j) o8[q * DM + lane + 64 * j] = o[j];
        __syncthreads();
    }

    // ---- phase 3b: Wo streamed once for all 8 queries, + bias, residual
    {
        float acc2[8];
        #pragma unroll
        for (int q = 0; q < 8; ++q) acc2[q] = 0.f;
        for (int d = 0; d < DM; d += 4) {
            float w0 = Wo[(d + 0) * DM + tid];
            float w1 = Wo[(d + 1) * DM + tid];
            float w2 = Wo[(d + 2) * DM + tid];
            float w3 = Wo[(d + 3) * DM + tid];
            #pragma unroll
            for (int q = 0; q < 8; ++q) {
                float4 ov = *(const float4*)&o8[q * DM + d];
                acc2[q] = fmaf(ov.x, w0, acc2[q]);
                acc2[q] = fmaf(ov.y, w1, acc2[q]);
                acc2[q] = fmaf(ov.z, w2, acc2[q]);
                acc2[q] = fmaf(ov.w, w3, acc2[q]);
            }
        }
        float bov = bo[tid];
        float rwv = rw[0];
        #pragma unroll
        for (int q = 0; q < 8; ++q) {
            size_t t = tq0 + q;
            out[t * DM + tid] = x[t * DM + tid] + (acc2[q] + bov) * rwv;
        }
    }
}

// ---------------------------------------------------------------------------
// Kernel C: FFN. Reads x_new from d_out, writes final output in place.
// ---------------------------------------------------------------------------
__global__ __launch_bounds__(256) void ffn_kernel(
    float* __restrict__ io,
    const float* __restrict__ gf, const float* __restrict__ bf,
    const float* __restrict__ W1, const float* __restrict__ b1f,
    const float* __restrict__ W2, const float* __restrict__ b2f,
    const float* __restrict__ rw)
{
    __shared__ __align__(16) float xs[8 * 256];
    __shared__ __align__(16) float xn[8 * 256];
    __shared__ __align__(16) float hg[8 * 1024];
    __shared__ float stat_m[8], stat_r[8];

    const int tid = threadIdx.x;
    const size_t t0 = (size_t)blockIdx.x * 8;

    for (int i = tid; i < 8 * 256; i += 256) xs[i] = io[t0 * DM + i];
    __syncthreads();
    {
        int tok = tid >> 5, l = tid & 31;
        float s = 0.f, s2 = 0.f;
        #pragma unroll
        for (int i = 0; i < 8; ++i) {
            float v = xs[tok * 256 + l + 32 * i];
            s += v; s2 += v * v;
        }
        #pragma unroll
        for (int m = 1; m < 32; m <<= 1) { s += __shfl_xor(s, m); s2 += __shfl_xor(s2, m); }
        if (l == 0) {
            float mean = s * (1.f / 256.f);
            float var  = s2 * (1.f / 256.f) - mean * mean;
            stat_m[tok] = mean;
            stat_r[tok] = rsqrtf(var + 1e-5f);
        }
    }
    __syncthreads();
    for (int i = tid; i < 8 * 256; i += 256) {
        int tok = i >> 8, d = i & 255;
        xn[i] = (xs[i] - stat_m[tok]) * stat_r[tok] * gf[d] + bf[d];
    }
    __syncthreads();

    {
        float a[4][8];
        #pragma unroll
        for (int c = 0; c < 4; ++c)
            #pragma unroll
            for (int t = 0; t < 8; ++t) a[c][t] = 0.f;
        for (int d = 0; d < 256; ++d) {
            float xv[8];
            #pragma unroll
            for (int t = 0; t < 8; ++t) xv[t] = xn[t * 256 + d];
            #pragma unroll
            for (int c = 0; c < 4; ++c) {
                float w = W1[d * DFF + tid + 256 * c];
                #pragma unroll
                for (int t = 0; t < 8; ++t) a[c][t] = fmaf(xv[t], w, a[c][t]);
            }
        }
        #pragma unroll
        for (int c = 0; c < 4; ++c) {
            float bb1 = b1f[tid + 256 * c];
            #pragma unroll
            for (int t = 0; t < 8; ++t) {
                float h = a[c][t] + bb1;
                hg[t * 1024 + tid + 256 * c] = 0.5f * h * (1.f + erff(h * 0.70710678118654752f));
            }
        }
    }
    __syncthreads();

    {
        float a2[8];
        #pragma unroll
        for (int t = 0; t < 8; ++t) a2[t] = 0.f;
        for (int i = 0; i < 1024; i += 4) {
            float w0 = W2[(i + 0) * DM + tid];
            float w1 = W2[(i + 1) * DM + tid];
            float w2 = W2[(i + 2) * DM + tid];
            float w3 = W2[(i + 3) * DM + tid];
            #pragma unroll
            for (int t = 0; t < 8; ++t) {
                float4 hv = *(const float4*)(hg + t * 1024 + i);
                a2[t] = fmaf(hv.x, w0, a2[t]);
                a2[t] = fmaf(hv.y, w1, a2[t]);
                a2[t] = fmaf(hv.z, w2, a2[t]);
                a2[t] = fmaf(hv.w, w3, a2[t]);
            }
        }
        float rwv = rw[0];
        float b2v = b2f[tid];
        #pragma unroll
        for (int t = 0; t < 8; ++t)
            io[(t0 + t) * DM + tid] = xs[t * 256 + tid] + (a2[t] + b2v) * rwv;
    }
}

// ---------------------------------------------------------------------------
extern "C" void kernel_launch(void* const* d_in, const int* in_sizes, int n_in,
                              void* d_out, int out_size, void* d_ws, size_t ws_size,
                              hipStream_t stream)
{
    const float* x   = (const float*)d_in[0];
    const float* Wq  = (const float*)d_in[1];
    const float* bq  = (const float*)d_in[2];
    const float* Wk  = (const float*)d_in[3];
    const float* bk  = (const float*)d_in[4];
    const float* Wv  = (const float*)d_in[5];
    const float* bv  = (const float*)d_in[6];
    const float* Wo  = (const float*)d_in[7];
    const float* bo  = (const float*)d_in[8];
    const float* g1  = (const float*)d_in[9];
    const float* b1  = (const float*)d_in[10];
    const float* gf  = (const float*)d_in[11];
    const float* bf  = (const float*)d_in[12];
    const float* W1  = (const float*)d_in[13];
    const float* b1f = (const float*)d_in[14];
    const float* W2  = (const float*)d_in[15];
    const float* b2f = (const float*)d_in[16];
    const float* rw  = (const float*)d_in[17];
    float* out = (float*)d_out;

    // workspace layout (~40 MB): qn | kn | knT | vall | knsq
    float* ws   = (float*)d_ws;
    float* qn   = ws;
    float* kn   = qn + (size_t)BATCH * SEQ * DQK;
    float* knT  = kn + (size_t)BATCH * SEQ * DQK;
    float* vall = knT + (size_t)BATCH * SEQ * DQK;
    float* knsq = vall + (size_t)BATCH * SEQ * DM;

    proj_kernel<<<BATCH * SEQ / 8, 256, 0, stream>>>(x, Wq, bq, Wk, bk, Wv, bv, g1, b1,
                                                     qn, kn, knT, knsq, vall);
    attn_kernel<<<BATCH * SEQ / 8, 256, 0, stream>>>(x, qn, kn, knT, knsq, vall,
                                                     Wo, bo, rw, out);
    ffn_kernel<<<BATCH * SEQ / 8, 256, 0, stream>>>(out, gf, bf, W1, b1f, W2, b2f, rw);
}

// Round 3
// 517.130 us; speedup vs baseline: 4.8409x; 1.6672x over previous
//
#include <hip/hip_runtime.h>
#include <math.h>

#define BATCH 8
#define SEQ   2048
#define DM    256
#define DQK   128
#define NHEADS 8
#define NK    16
#define DFF   1024

typedef __attribute__((ext_vector_type(8))) short short8;
typedef __attribute__((ext_vector_type(4))) float floatx4;

__device__ __forceinline__ unsigned short f2bf(float f) {
    unsigned int u = __float_as_uint(f);
    u += 0x7fffu + ((u >> 16) & 1u);          // round-to-nearest-even
    return (unsigned short)(u >> 16);
}

__device__ __forceinline__ float gelu_fast(float h) {
    // tanh-form GELU; max abs dev vs exact-erf ~3e-4 (vs 0.1 threshold)
    float y = 0.7978845608028654f * (h + 0.044715f * h * h * h);
    float e = __expf(2.f * y);
    float t = 1.f - 2.f / (e + 1.f);
    return 0.5f * h * (1.f + t);
}

// ---------------------------------------------------------------------------
// Kernel W: repack W1 (256x1024) and W2 (1024x256) fp32 -> bf16 in MFMA
// B-fragment order: element j of group (nt,kk,lane) = W[k= kk*32+(lane>>4)*8+j]
// [n= nt*16+(lane&15)]. Makes the FFN K-loop's B loads coalesced dwordx4.
// ---------------------------------------------------------------------------
__global__ __launch_bounds__(256) void conv_kernel(
    const float* __restrict__ W1, const float* __restrict__ W2,
    unsigned short* __restrict__ W1f, unsigned short* __restrict__ W2f)
{
    int g = blockIdx.x * 256 + threadIdx.x;
    if (g < 32768) {                       // W1f: nt 0..63, kk 0..7, lane 0..63
        int lane = g & 63, kk = (g >> 6) & 7, nt = g >> 9;
        int n = nt * 16 + (lane & 15);
        int k0 = kk * 32 + (lane >> 4) * 8;
        unsigned int pk[4];
        #pragma unroll
        for (int jj = 0; jj < 4; ++jj) {
            unsigned short lo = f2bf(W1[(size_t)(k0 + 2 * jj) * DFF + n]);
            unsigned short hi = f2bf(W1[(size_t)(k0 + 2 * jj + 1) * DFF + n]);
            pk[jj] = (unsigned int)lo | ((unsigned int)hi << 16);
        }
        *(uint4*)(W1f + (size_t)g * 8) = make_uint4(pk[0], pk[1], pk[2], pk[3]);
    } else {                               // W2f: nt 0..15, kk 0..31, lane 0..63
        int h = g - 32768;
        int lane = h & 63, kk = (h >> 6) & 31, nt = h >> 11;
        int n = nt * 16 + (lane & 15);
        int k0 = kk * 32 + (lane >> 4) * 8;
        unsigned int pk[4];
        #pragma unroll
        for (int jj = 0; jj < 4; ++jj) {
            unsigned short lo = f2bf(W2[(size_t)(k0 + 2 * jj) * DM + n]);
            unsigned short hi = f2bf(W2[(size_t)(k0 + 2 * jj + 1) * DM + n]);
            pk[jj] = (unsigned int)lo | ((unsigned int)hi << 16);
        }
        *(uint4*)(W2f + (size_t)h * 8) = make_uint4(pk[0], pk[1], pk[2], pk[3]);
    }
}

// ---------------------------------------------------------------------------
// Kernel A: per-token projections (unchanged from round 2).
// ---------------------------------------------------------------------------
__global__ __launch_bounds__(256) void proj_kernel(
    const float* __restrict__ x,
    const float* __restrict__ Wq, const float* __restrict__ bq,
    const float* __restrict__ Wk, const float* __restrict__ bk,
    const float* __restrict__ Wv, const float* __restrict__ bv,
    const float* __restrict__ g1, const float* __restrict__ b1,
    float* __restrict__ qn, float* __restrict__ kn, float* __restrict__ knT,
    float* __restrict__ knsq, float* __restrict__ vall)
{
    __shared__ __align__(16) float xs[8 * 256];
    __shared__ __align__(16) float xn[8 * 256];
    __shared__ __align__(16) float ks[8 * 128];
    __shared__ float stat_m[8], stat_r[8];
    __shared__ float nred[8][2], kred[8][2], k2red[8][2];

    const int tid = threadIdx.x;
    const int b = blockIdx.x & 7;
    const int chunk = blockIdx.x >> 3;
    const size_t t0 = (size_t)b * SEQ + (size_t)chunk * 8;

    for (int i = tid; i < 8 * 256; i += 256) xs[i] = x[t0 * DM + i];
    __syncthreads();

    {
        int tok = tid >> 5, l = tid & 31;
        float s = 0.f, s2 = 0.f;
        #pragma unroll
        for (int i = 0; i < 8; ++i) {
            float v = xs[tok * 256 + l + 32 * i];
            s += v; s2 += v * v;
        }
        #pragma unroll
        for (int m = 1; m < 32; m <<= 1) { s += __shfl_xor(s, m); s2 += __shfl_xor(s2, m); }
        if (l == 0) {
            float mean = s * (1.f / 256.f);
            float var  = s2 * (1.f / 256.f) - mean * mean;
            stat_m[tok] = mean;
            stat_r[tok] = rsqrtf(var + 1e-5f);
        }
    }
    __syncthreads();
    for (int i = tid; i < 8 * 256; i += 256) {
        int tok = i >> 8, d = i & 255;
        xn[i] = (xs[i] - stat_m[tok]) * stat_r[tok] * g1[d] + b1[d];
    }
    __syncthreads();

    {
        const int col = tid & 127, half = tid >> 7;
        float qa[4] = {0.f, 0.f, 0.f, 0.f}, ka[4] = {0.f, 0.f, 0.f, 0.f};
        for (int d = 0; d < 256; ++d) {
            float wq = Wq[d * DQK + col];
            float wk = Wk[d * DQK + col];
            #pragma unroll
            for (int t = 0; t < 4; ++t) {
                float xv = xs[(half * 4 + t) * 256 + d];
                qa[t] = fmaf(xv, wq, qa[t]);
                ka[t] = fmaf(xv, wk, ka[t]);
            }
        }
        #pragma unroll
        for (int t = 0; t < 4; ++t) { qa[t] += bq[col]; ka[t] += bk[col]; }

        const int sub = (tid >> 6) & 1;
        #pragma unroll
        for (int t = 0; t < 4; ++t) {
            float sq = qa[t] * qa[t], sk = ka[t] * ka[t];
            #pragma unroll
            for (int m = 1; m < 64; m <<= 1) { sq += __shfl_xor(sq, m); sk += __shfl_xor(sk, m); }
            if ((tid & 63) == 0) { nred[half * 4 + t][sub] = sq; kred[half * 4 + t][sub] = sk; }
        }
        __syncthreads();
        float kvv[4];
        #pragma unroll
        for (int t = 0; t < 4; ++t) {
            int tok = half * 4 + t;
            float nq = sqrtf(nred[tok][0] + nred[tok][1]);
            float nk = sqrtf(kred[tok][0] + kred[tok][1]);
            float qv = qa[t] / fmaxf(nq, 1e-12f);
            float kv = ka[t] / fmaxf(nk, 1e-12f);
            qn[(t0 + tok) * DQK + col] = qv;
            kn[(t0 + tok) * DQK + col] = kv;
            ks[tok * 128 + col] = kv;
            kvv[t] = kv;
        }
        #pragma unroll
        for (int t = 0; t < 4; ++t) {
            float s2 = kvv[t] * kvv[t];
            #pragma unroll
            for (int m = 1; m < 64; m <<= 1) s2 += __shfl_xor(s2, m);
            if ((tid & 63) == 0) k2red[half * 4 + t][sub] = s2;
        }
        __syncthreads();
        if (tid < 8) knsq[t0 + tid] = k2red[tid][0] + k2red[tid][1];
    }

    if (tid < 128) {
        float tmp[8];
        #pragma unroll
        for (int t = 0; t < 8; ++t) tmp[t] = ks[t * 128 + tid];
        float* dst = knT + ((size_t)b * DQK + tid) * SEQ + (size_t)chunk * 8;
        *(float4*)(dst)     = make_float4(tmp[0], tmp[1], tmp[2], tmp[3]);
        *(float4*)(dst + 4) = make_float4(tmp[4], tmp[5], tmp[6], tmp[7]);
    }

    {
        float va[8] = {0.f, 0.f, 0.f, 0.f, 0.f, 0.f, 0.f, 0.f};
        for (int d = 0; d < 256; ++d) {
            float w = Wv[d * DM + tid];
            #pragma unroll
            for (int t = 0; t < 8; ++t) va[t] = fmaf(xn[t * 256 + d], w, va[t]);
        }
        float bvv = bv[tid];
        #pragma unroll
        for (int t = 0; t < 8; ++t) vall[(t0 + t) * DM + tid] = va[t] + bvv;
    }
}

// ---------------------------------------------------------------------------
// Kernel B: scores + exact top-16 + MHA + Wo + residual (unchanged round 2).
// ---------------------------------------------------------------------------
__global__ __launch_bounds__(256, 2) void attn_kernel(
    const float* __restrict__ x,
    const float* __restrict__ qn_g, const float* __restrict__ kn_g,
    const float* __restrict__ knT, const float* __restrict__ knsq_g,
    const float* __restrict__ vall,
    const float* __restrict__ Wo, const float* __restrict__ bo,
    const float* __restrict__ rw, float* __restrict__ out)
{
    __shared__ __align__(16) float s_ld[4 * SEQ];
    __shared__ __align__(16) float qs[8 * DQK];
    __shared__ __align__(16) float attn_s[8 * 128];
    __shared__ __align__(16) float o8[8 * DM];
    __shared__ int topidx[8 * NK];

    const int tid = threadIdx.x;
    const int lane = tid & 63, wave = tid >> 6;
    const int b = blockIdx.x & 7;
    const int chunk = blockIdx.x >> 3;
    const size_t tq0 = (size_t)b * SEQ + (size_t)chunk * 8;
    const size_t rowb = (size_t)b * SEQ;

    *(float4*)&qs[tid * 4] = *(const float4*)&qn_g[tq0 * DQK + tid * 4];
    __syncthreads();

    float acc[8][8];
    #pragma unroll
    for (int q = 0; q < 8; ++q)
        #pragma unroll
        for (int k = 0; k < 8; ++k) acc[q][k] = 0.f;

    const float* kTb = knT + (size_t)b * DQK * SEQ;
    const int key0 = tid * 8;
    for (int d = 0; d < DQK; d += 4) {
        float kv[4][8];
        #pragma unroll
        for (int dd = 0; dd < 4; ++dd) {
            *(float4*)&kv[dd][0] = *(const float4*)&kTb[(size_t)(d + dd) * SEQ + key0];
            *(float4*)&kv[dd][4] = *(const float4*)&kTb[(size_t)(d + dd) * SEQ + key0 + 4];
        }
        #pragma unroll
        for (int q = 0; q < 8; ++q) {
            float4 qv = *(const float4*)&qs[q * DQK + d];
            float qq[4] = {qv.x, qv.y, qv.z, qv.w};
            #pragma unroll
            for (int dd = 0; dd < 4; ++dd)
                #pragma unroll
                for (int k = 0; k < 8; ++k)
                    acc[q][k] = fmaf(qq[dd], kv[dd][k], acc[q][k]);
        }
    }

    float ksq[8];
    {
        const float* ksqb = knsq_g + rowb + key0;
        float4 a = *(const float4*)(ksqb);
        float4 c = *(const float4*)(ksqb + 4);
        ksq[0] = a.x; ksq[1] = a.y; ksq[2] = a.z; ksq[3] = a.w;
        ksq[4] = c.x; ksq[5] = c.y; ksq[6] = c.z; ksq[7] = c.w;
    }

    for (int p = 0; p < 2; ++p) {
        __syncthreads();
        #pragma unroll
        for (int qq = 0; qq < 4; ++qq) {
            int q = 4 * p + qq;
            #pragma unroll
            for (int j = 0; j < 8; ++j)
                s_ld[qq * SEQ + key0 + j] = 2.f * acc[q][j] - ksq[j];
        }
        __syncthreads();
        {
            float v[32];
            #pragma unroll
            for (int i = 0; i < 32; ++i) v[i] = s_ld[wave * SEQ + lane + 64 * i];
            const int qg = 4 * p + wave;
            for (int r = 0; r < NK; ++r) {
                float bv = v[0]; int bi = 0;
                #pragma unroll
                for (int i = 1; i < 32; ++i)
                    if (v[i] > bv) { bv = v[i]; bi = i; }
                int gi = lane + 64 * bi;
                #pragma unroll
                for (int m = 1; m < 64; m <<= 1) {
                    float ov = __shfl_xor(bv, m);
                    int   oi = __shfl_xor(gi, m);
                    if (ov > bv || (ov == bv && oi < gi)) { bv = ov; gi = oi; }
                }
                if (lane == (gi & 63)) {
                    int slot = gi >> 6;
                    #pragma unroll
                    for (int i = 0; i < 32; ++i)
                        if (slot == i) v[i] = -INFINITY;
                }
                if (lane == 0) topidx[qg * NK + r] = gi;
            }
        }
    }
    __syncthreads();

    for (int qq = 0; qq < 2; ++qq) {
        const int q = wave + 4 * qq;
        const int h = lane >> 3;
        const int k1 = lane & 7, k2 = 8 + (lane & 7);
        const int i1 = topidx[q * NK + k1], i2 = topidx[q * NK + k2];
        const float* kr1 = kn_g + (rowb + i1) * DQK + h * 16;
        const float* kr2 = kn_g + (rowb + i2) * DQK + h * 16;
        float lg1 = 0.f, lg2 = 0.f;
        #pragma unroll
        for (int d = 0; d < 16; d += 4) {
            float4 qv = *(const float4*)&qs[q * DQK + h * 16 + d];
            float4 a1 = *(const float4*)&kr1[d];
            float4 a2 = *(const float4*)&kr2[d];
            lg1 = fmaf(qv.x, a1.x, lg1); lg1 = fmaf(qv.y, a1.y, lg1);
            lg1 = fmaf(qv.z, a1.z, lg1); lg1 = fmaf(qv.w, a1.w, lg1);
            lg2 = fmaf(qv.x, a2.x, lg2); lg2 = fmaf(qv.y, a2.y, lg2);
            lg2 = fmaf(qv.z, a2.z, lg2); lg2 = fmaf(qv.w, a2.w, lg2);
        }
        lg1 *= 0.25f; lg2 *= 0.25f;
        float mx = fmaxf(lg1, lg2);
        #pragma unroll
        for (int m = 1; m < 8; m <<= 1) mx = fmaxf(mx, __shfl_xor(mx, m));
        float e1 = expf(lg1 - mx), e2 = expf(lg2 - mx);
        float ssum = e1 + e2;
        #pragma unroll
        for (int m = 1; m < 8; m <<= 1) ssum += __shfl_xor(ssum, m);
        attn_s[q * 128 + h * 16 + k1] = e1 / ssum;
        attn_s[q * 128 + h * 16 + k2] = e2 / ssum;
        __syncthreads();

        float o[4] = {0.f, 0.f, 0.f, 0.f};
        for (int k = 0; k < NK; ++k) {
            const float* vr = vall + (rowb + topidx[q * NK + k]) * DM;
            #pragma unroll
            for (int j = 0; j < 4; ++j) {
                int d = lane + 64 * j;
                o[j] = fmaf(attn_s[q * 128 + (d >> 5) * 16 + k], vr[d], o[j]);
            }
        }
        #pragma unroll
        for (int j = 0; j < 4; ++j) o8[q * DM + lane + 64 * j] = o[j];
        __syncthreads();
    }

    {
        float acc2[8];
        #pragma unroll
        for (int q = 0; q < 8; ++q) acc2[q] = 0.f;
        for (int d = 0; d < DM; d += 4) {
            float w0 = Wo[(d + 0) * DM + tid];
            float w1 = Wo[(d + 1) * DM + tid];
            float w2 = Wo[(d + 2) * DM + tid];
            float w3 = Wo[(d + 3) * DM + tid];
            #pragma unroll
            for (int q = 0; q < 8; ++q) {
                float4 ov = *(const float4*)&o8[q * DM + d];
                acc2[q] = fmaf(ov.x, w0, acc2[q]);
                acc2[q] = fmaf(ov.y, w1, acc2[q]);
                acc2[q] = fmaf(ov.z, w2, acc2[q]);
                acc2[q] = fmaf(ov.w, w3, acc2[q]);
            }
        }
        float bov = bo[tid];
        float rwv = rw[0];
        #pragma unroll
        for (int q = 0; q < 8; ++q) {
            size_t t = tq0 + q;
            out[t * DM + tid] = x[t * DM + tid] + (acc2[q] + bov) * rwv;
        }
    }
}

// ---------------------------------------------------------------------------
// Kernel C: FFN via bf16 MFMA. 16 tokens/block, 4 waves.
// GEMM1: wave n-chunk 256 of DFF (16 n-tiles x 8 k-steps).
// GEMM2: wave n-chunk 64 of DM (4 n-tiles x 32 k-steps), A from LDS.
// ---------------------------------------------------------------------------
__global__ __launch_bounds__(256, 2) void ffn_kernel(
    float* __restrict__ io,
    const float* __restrict__ gf, const float* __restrict__ bf,
    const unsigned short* __restrict__ W1f, const float* __restrict__ b1f,
    const unsigned short* __restrict__ W2f, const float* __restrict__ b2f,
    const float* __restrict__ rw)
{
    __shared__ __align__(16) float xs[16][260];          // fp32 x, padded
    __shared__ float gfs[256], bfs[256], b2s[256], b1s[1024];
    __shared__ float stat_m[16], stat_r[16];
    __shared__ __align__(16) unsigned short Af[8 * 64 * 8];   // A-frags GEMM1, 8KB
    __shared__ __align__(16) unsigned short G[16][1032];      // gelu(h) bf16, 33KB

    const int tid = threadIdx.x;
    const int lane = tid & 63, wave = tid >> 6;
    const int quad = lane >> 4, lr = lane & 15;
    const size_t t0 = (size_t)blockIdx.x * 16;

    for (int i = tid; i < 16 * 256; i += 256) xs[i >> 8][i & 255] = io[t0 * DM + i];
    gfs[tid] = gf[tid]; bfs[tid] = bf[tid]; b2s[tid] = b2f[tid];
    for (int i = tid; i < 1024; i += 256) b1s[i] = b1f[i];
    __syncthreads();

    // LayerNorm stats: 16 lanes per token
    {
        int tok = tid >> 4, l = tid & 15;
        float s = 0.f, s2 = 0.f;
        #pragma unroll
        for (int i = 0; i < 16; ++i) {
            float v = xs[tok][l + 16 * i];
            s += v; s2 += v * v;
        }
        #pragma unroll
        for (int m = 1; m < 16; m <<= 1) { s += __shfl_xor(s, m); s2 += __shfl_xor(s2, m); }
        if (l == 0) {
            float mean = s * (1.f / 256.f);
            float var  = s2 * (1.f / 256.f) - mean * mean;
            stat_m[tok] = mean;
            stat_r[tok] = rsqrtf(var + 1e-5f);
        }
    }
    __syncthreads();

    // Build A-fragments for GEMM1 (LN applied, bf16, fragment order)
    for (int kk = wave; kk < 8; kk += 4) {
        int m = lr, k0 = kk * 32 + quad * 8;
        float mm = stat_m[m], rr = stat_r[m];
        unsigned int pk[4];
        #pragma unroll
        for (int jj = 0; jj < 4; ++jj) {
            int ka = k0 + 2 * jj, kb = ka + 1;
            float v0 = (xs[m][ka] - mm) * rr * gfs[ka] + bfs[ka];
            float v1 = (xs[m][kb] - mm) * rr * gfs[kb] + bfs[kb];
            pk[jj] = (unsigned int)f2bf(v0) | ((unsigned int)f2bf(v1) << 16);
        }
        *(uint4*)&Af[(kk * 64 + lane) * 8] = make_uint4(pk[0], pk[1], pk[2], pk[3]);
    }
    __syncthreads();

    short8 afr[8];
    #pragma unroll
    for (int kk = 0; kk < 8; ++kk)
        afr[kk] = *(const short8*)&Af[(kk * 64 + lane) * 8];

    // GEMM1: H[16][1024], this wave covers n in [wave*256, wave*256+256)
    floatx4 acc[16];
    #pragma unroll
    for (int nt = 0; nt < 16; ++nt) acc[nt] = (floatx4){0.f, 0.f, 0.f, 0.f};

    const unsigned short* w1p = W1f + ((size_t)(wave * 16) * 8 * 64) * 8;
    for (int nt = 0; nt < 16; ++nt) {
        #pragma unroll
        for (int kk = 0; kk < 8; ++kk) {
            short8 bfr = *(const short8*)(w1p + (size_t)((nt * 8 + kk) * 64 + lane) * 8);
            acc[nt] = __builtin_amdgcn_mfma_f32_16x16x32_bf16(afr[kk], bfr, acc[nt], 0, 0, 0);
        }
    }

    // epilogue 1: bias + GELU -> G (bf16)
    #pragma unroll
    for (int nt = 0; nt < 16; ++nt) {
        #pragma unroll
        for (int reg = 0; reg < 4; ++reg) {
            int n = wave * 256 + nt * 16 + lr;
            int row = quad * 4 + reg;
            float h = acc[nt][reg] + b1s[n];
            G[row][n] = f2bf(gelu_fast(h));
        }
    }
    __syncthreads();

    // GEMM2: O[16][256], this wave covers n in [wave*64, wave*64+64)
    floatx4 acc2[4];
    #pragma unroll
    for (int nt = 0; nt < 4; ++nt) acc2[nt] = (floatx4){0.f, 0.f, 0.f, 0.f};

    for (int kk2 = 0; kk2 < 32; ++kk2) {
        short8 a2 = *(const short8*)&G[lr][kk2 * 32 + quad * 8];
        #pragma unroll
        for (int nt = 0; nt < 4; ++nt) {
            short8 b2 = *(const short8*)(W2f + (size_t)(((wave * 4 + nt) * 32 + kk2) * 64 + lane) * 8);
            acc2[nt] = __builtin_amdgcn_mfma_f32_16x16x32_bf16(a2, b2, acc2[nt], 0, 0, 0);
        }
    }

    // epilogue 2: out = x + (o + b2f) * rw
    float rwv = rw[0];
    #pragma unroll
    for (int nt = 0; nt < 4; ++nt) {
        #pragma unroll
        for (int reg = 0; reg < 4; ++reg) {
            int col = wave * 64 + nt * 16 + lr;
            int row = quad * 4 + reg;
            float o = acc2[nt][reg] + b2s[col];
            io[(t0 + row) * DM + col] = xs[row][col] + o * rwv;
        }
    }
}

// ---------------------------------------------------------------------------
extern "C" void kernel_launch(void* const* d_in, const int* in_sizes, int n_in,
                              void* d_out, int out_size, void* d_ws, size_t ws_size,
                              hipStream_t stream)
{
    const float* x   = (const float*)d_in[0];
    const float* Wq  = (const float*)d_in[1];
    const float* bq  = (const float*)d_in[2];
    const float* Wk  = (const float*)d_in[3];
    const float* bk  = (const float*)d_in[4];
    const float* Wv  = (const float*)d_in[5];
    const float* bv  = (const float*)d_in[6];
    const float* Wo  = (const float*)d_in[7];
    const float* bo  = (const float*)d_in[8];
    const float* g1  = (const float*)d_in[9];
    const float* b1  = (const float*)d_in[10];
    const float* gf  = (const float*)d_in[11];
    const float* bf  = (const float*)d_in[12];
    const float* W1  = (const float*)d_in[13];
    const float* b1f = (const float*)d_in[14];
    const float* W2  = (const float*)d_in[15];
    const float* b2f = (const float*)d_in[16];
    const float* rw  = (const float*)d_in[17];
    float* out = (float*)d_out;

    // workspace layout (~41 MB): qn | kn | knT | vall | knsq | W1f | W2f
    float* ws   = (float*)d_ws;
    float* qn   = ws;
    float* kn   = qn + (size_t)BATCH * SEQ * DQK;
    float* knT  = kn + (size_t)BATCH * SEQ * DQK;
    float* vall = knT + (size_t)BATCH * SEQ * DQK;
    float* knsq = vall + (size_t)BATCH * SEQ * DM;
    unsigned short* W1f = (unsigned short*)(knsq + BATCH * SEQ);
    unsigned short* W2f = W1f + (size_t)DM * DFF;

    conv_kernel<<<256, 256, 0, stream>>>(W1, W2, W1f, W2f);
    proj_kernel<<<BATCH * SEQ / 8, 256, 0, stream>>>(x, Wq, bq, Wk, bk, Wv, bv, g1, b1,
                                                     qn, kn, knT, knsq, vall);
    attn_kernel<<<BATCH * SEQ / 8, 256, 0, stream>>>(x, qn, kn, knT, knsq, vall,
                                                     Wo, bo, rw, out);
    ffn_kernel<<<BATCH * SEQ / 16, 256, 0, stream>>>(out, gf, bf, W1f, b1f, W2f, b2f, rw);
}

// Round 4
// 515.633 us; speedup vs baseline: 4.8549x; 1.0029x over previous
//
#include <hip/hip_runtime.h>
#include <math.h>

#define BATCH 8
#define SEQ   2048
#define DM    256
#define DQK   128
#define NHEADS 8
#define NK    16
#define DFF   1024

typedef __attribute__((ext_vector_type(8))) short short8;
typedef __attribute__((ext_vector_type(8))) _Float16 half8;
typedef __attribute__((ext_vector_type(4))) float floatx4;

__device__ __forceinline__ unsigned short f2bf(float f) {
    unsigned int u = __float_as_uint(f);
    u += 0x7fffu + ((u >> 16) & 1u);          // round-to-nearest-even
    return (unsigned short)(u >> 16);
}

__device__ __forceinline__ float gelu_fast(float h) {
    float y = 0.7978845608028654f * (h + 0.044715f * h * h * h);
    float e = __expf(2.f * y);
    float t = 1.f - 2.f / (e + 1.f);
    return 0.5f * h * (1.f + t);
}

// ---------------------------------------------------------------------------
// Kernel W: repack W1/W2 fp32 -> bf16 MFMA B-fragment order (unchanged R3).
// ---------------------------------------------------------------------------
__global__ __launch_bounds__(256) void conv_kernel(
    const float* __restrict__ W1, const float* __restrict__ W2,
    unsigned short* __restrict__ W1f, unsigned short* __restrict__ W2f)
{
    int g = blockIdx.x * 256 + threadIdx.x;
    if (g < 32768) {
        int lane = g & 63, kk = (g >> 6) & 7, nt = g >> 9;
        int n = nt * 16 + (lane & 15);
        int k0 = kk * 32 + (lane >> 4) * 8;
        unsigned int pk[4];
        #pragma unroll
        for (int jj = 0; jj < 4; ++jj) {
            unsigned short lo = f2bf(W1[(size_t)(k0 + 2 * jj) * DFF + n]);
            unsigned short hi = f2bf(W1[(size_t)(k0 + 2 * jj + 1) * DFF + n]);
            pk[jj] = (unsigned int)lo | ((unsigned int)hi << 16);
        }
        *(uint4*)(W1f + (size_t)g * 8) = make_uint4(pk[0], pk[1], pk[2], pk[3]);
    } else {
        int h = g - 32768;
        int lane = h & 63, kk = (h >> 6) & 31, nt = h >> 11;
        int n = nt * 16 + (lane & 15);
        int k0 = kk * 32 + (lane >> 4) * 8;
        unsigned int pk[4];
        #pragma unroll
        for (int jj = 0; jj < 4; ++jj) {
            unsigned short lo = f2bf(W2[(size_t)(k0 + 2 * jj) * DM + n]);
            unsigned short hi = f2bf(W2[(size_t)(k0 + 2 * jj + 1) * DM + n]);
            pk[jj] = (unsigned int)lo | ((unsigned int)hi << 16);
        }
        *(uint4*)(W2f + (size_t)h * 8) = make_uint4(pk[0], pk[1], pk[2], pk[3]);
    }
}

// ---------------------------------------------------------------------------
// Kernel A: projections. Writes qn (fp32), kn hi/lo (f16 split), knsq, vall.
// ---------------------------------------------------------------------------
__global__ __launch_bounds__(256) void proj_kernel(
    const float* __restrict__ x,
    const float* __restrict__ Wq, const float* __restrict__ bq,
    const float* __restrict__ Wk, const float* __restrict__ bk,
    const float* __restrict__ Wv, const float* __restrict__ bv,
    const float* __restrict__ g1, const float* __restrict__ b1,
    float* __restrict__ qn, _Float16* __restrict__ knh, _Float16* __restrict__ knl,
    float* __restrict__ knsq, float* __restrict__ vall)
{
    __shared__ __align__(16) float xs[8 * 256];
    __shared__ __align__(16) float xn[8 * 256];
    __shared__ float stat_m[8], stat_r[8];
    __shared__ float nred[8][2], kred[8][2], k2red[8][2];

    const int tid = threadIdx.x;
    const int b = blockIdx.x & 7;
    const int chunk = blockIdx.x >> 3;
    const size_t t0 = (size_t)b * SEQ + (size_t)chunk * 8;

    for (int i = tid; i < 8 * 256; i += 256) xs[i] = x[t0 * DM + i];
    __syncthreads();

    {
        int tok = tid >> 5, l = tid & 31;
        float s = 0.f, s2 = 0.f;
        #pragma unroll
        for (int i = 0; i < 8; ++i) {
            float v = xs[tok * 256 + l + 32 * i];
            s += v; s2 += v * v;
        }
        #pragma unroll
        for (int m = 1; m < 32; m <<= 1) { s += __shfl_xor(s, m); s2 += __shfl_xor(s2, m); }
        if (l == 0) {
            float mean = s * (1.f / 256.f);
            float var  = s2 * (1.f / 256.f) - mean * mean;
            stat_m[tok] = mean;
            stat_r[tok] = rsqrtf(var + 1e-5f);
        }
    }
    __syncthreads();
    for (int i = tid; i < 8 * 256; i += 256) {
        int tok = i >> 8, d = i & 255;
        xn[i] = (xs[i] - stat_m[tok]) * stat_r[tok] * g1[d] + b1[d];
    }
    __syncthreads();

    {
        const int col = tid & 127, half = tid >> 7;
        float qa[4] = {0.f, 0.f, 0.f, 0.f}, ka[4] = {0.f, 0.f, 0.f, 0.f};
        for (int d = 0; d < 256; ++d) {
            float wq = Wq[d * DQK + col];
            float wk = Wk[d * DQK + col];
            #pragma unroll
            for (int t = 0; t < 4; ++t) {
                float xv = xs[(half * 4 + t) * 256 + d];
                qa[t] = fmaf(xv, wq, qa[t]);
                ka[t] = fmaf(xv, wk, ka[t]);
            }
        }
        #pragma unroll
        for (int t = 0; t < 4; ++t) { qa[t] += bq[col]; ka[t] += bk[col]; }

        const int sub = (tid >> 6) & 1;
        #pragma unroll
        for (int t = 0; t < 4; ++t) {
            float sq = qa[t] * qa[t], sk = ka[t] * ka[t];
            #pragma unroll
            for (int m = 1; m < 64; m <<= 1) { sq += __shfl_xor(sq, m); sk += __shfl_xor(sk, m); }
            if ((tid & 63) == 0) { nred[half * 4 + t][sub] = sq; kred[half * 4 + t][sub] = sk; }
        }
        __syncthreads();
        float kvv[4];
        #pragma unroll
        for (int t = 0; t < 4; ++t) {
            int tok = half * 4 + t;
            float nq = sqrtf(nred[tok][0] + nred[tok][1]);
            float nk = sqrtf(kred[tok][0] + kred[tok][1]);
            float qv = qa[t] / fmaxf(nq, 1e-12f);
            float kv = ka[t] / fmaxf(nk, 1e-12f);
            qn[(t0 + tok) * DQK + col] = qv;
            _Float16 h = (_Float16)kv;
            knh[(t0 + tok) * DQK + col] = h;
            knl[(t0 + tok) * DQK + col] = (_Float16)(kv - (float)h);
            kvv[t] = kv;
        }
        #pragma unroll
        for (int t = 0; t < 4; ++t) {
            float s2 = kvv[t] * kvv[t];
            #pragma unroll
            for (int m = 1; m < 64; m <<= 1) s2 += __shfl_xor(s2, m);
            if ((tid & 63) == 0) k2red[half * 4 + t][sub] = s2;
        }
        __syncthreads();
        if (tid < 8) knsq[t0 + tid] = k2red[tid][0] + k2red[tid][1];
    }

    {
        float va[8] = {0.f, 0.f, 0.f, 0.f, 0.f, 0.f, 0.f, 0.f};
        for (int d = 0; d < 256; ++d) {
            float w = Wv[d * DM + tid];
            #pragma unroll
            for (int t = 0; t < 8; ++t) va[t] = fmaf(xn[t * 256 + d], w, va[t]);
        }
        float bvv = bv[tid];
        #pragma unroll
        for (int t = 0; t < 8; ++t) vall[(t0 + t) * DM + tid] = va[t] + bvv;
    }
}

// ---------------------------------------------------------------------------
// Kernel B: 16 queries/block, 512 threads (8 waves). Scores via f16-split
// MFMA (fp32-accurate). Wave owns 256 keys; scores live in 64 VGPRs
// (C-layout). Top-16 = cached hierarchical argmax (lane -> quad -> wave ->
// block) with owner-only rescan. Then MHA + Wo + residual.
// ---------------------------------------------------------------------------
__global__ __launch_bounds__(512, 4) void attn_kernel(
    const float* __restrict__ x,
    const float* __restrict__ qn_g,
    const _Float16* __restrict__ knh, const _Float16* __restrict__ knl,
    const float* __restrict__ knsq_g, const float* __restrict__ vall,
    const float* __restrict__ Wo, const float* __restrict__ bo,
    const float* __restrict__ rw, float* __restrict__ out)
{
    __shared__ __align__(16) float qs[16][132];       // 8.25 KB
    __shared__ __align__(16) float attn_s[16][132];   // 8.25 KB
    __shared__ __align__(16) float o16[16][260];      // 16.25 KB
    __shared__ float cand_val[16][8];
    __shared__ int   cand_idx[16][8];
    __shared__ int   gtop[16][16];

    const int tid = threadIdx.x;
    const int lane = tid & 63, wave = tid >> 6;
    const int quad = lane >> 4, lr = lane & 15;
    const int b = blockIdx.x & 7;
    const int chunk = blockIdx.x >> 3;
    const size_t tq0 = (size_t)b * SEQ + (size_t)chunk * 16;
    const size_t rowb = (size_t)b * SEQ;

    for (int i = tid; i < 16 * 128; i += 512)
        qs[i >> 7][i & 127] = qn_g[tq0 * DQK + i];
    __syncthreads();

    // A-fragments: f16 hi/lo split of the 16 query rows
    half8 ah[4], al[4];
    #pragma unroll
    for (int s = 0; s < 4; ++s) {
        #pragma unroll
        for (int j = 0; j < 8; ++j) {
            float v = qs[lr][s * 32 + quad * 8 + j];
            _Float16 h = (_Float16)v;
            ah[s][j] = h;
            al[s][j] = (_Float16)(v - (float)h);
        }
    }

    // ---- phase 1: MFMA scores. Wave covers keys [wave*256, wave*256+256).
    const int wbase = wave * 256;
    const _Float16* khb = knh + rowb * DQK;
    const _Float16* klb = knl + rowb * DQK;
    float sc[16][4];
    #pragma unroll
    for (int t = 0; t < 16; ++t) {
        const int key = wbase + t * 16 + lr;
        floatx4 acc = (floatx4){0.f, 0.f, 0.f, 0.f};
        const _Float16* ph = khb + (size_t)key * DQK + quad * 8;
        const _Float16* pl = klb + (size_t)key * DQK + quad * 8;
        #pragma unroll
        for (int s = 0; s < 4; ++s) {
            half8 bh = *(const half8*)(ph + s * 32);
            half8 bl = *(const half8*)(pl + s * 32);
            acc = __builtin_amdgcn_mfma_f32_16x16x32_f16(al[s], bh, acc, 0, 0, 0);
            acc = __builtin_amdgcn_mfma_f32_16x16x32_f16(ah[s], bl, acc, 0, 0, 0);
            acc = __builtin_amdgcn_mfma_f32_16x16x32_f16(ah[s], bh, acc, 0, 0, 0);
        }
        float kq = knsq_g[rowb + key];
        #pragma unroll
        for (int r = 0; r < 4; ++r) sc[t][r] = 2.f * acc[r] - kq;
    }

    // ---- phase 2: exact top-16 per query (tiebreak: lowest key index).
    // bootstrap: per-lane argmax (16 vals) -> quad reduce -> per-wave cand.
    #pragma unroll
    for (int r = 0; r < 4; ++r) {
        float bv = sc[0][r]; int bs = 0;
        #pragma unroll
        for (int t = 1; t < 16; ++t)
            if (sc[t][r] > bv) { bv = sc[t][r]; bs = t; }   // strict: min slot on tie
        int gi = wbase + bs * 16 + lr;
        #pragma unroll
        for (int m = 1; m < 16; m <<= 1) {
            float ov = __shfl_xor(bv, m);
            int   oi = __shfl_xor(gi, m);
            if (ov > bv || (ov == bv && oi < gi)) { bv = ov; gi = oi; }
        }
        if (lr == 0) { cand_val[quad * 4 + r][wave] = bv; cand_idx[quad * 4 + r][wave] = gi; }
    }

    for (int rnd = 0; rnd < NK; ++rnd) {
        __syncthreads();
        if (tid < 16) {               // lane tid owns query row tid
            float bv = cand_val[tid][0]; int gi = cand_idx[tid][0];
            #pragma unroll
            for (int w = 1; w < 8; ++w) {
                float ov = cand_val[tid][w]; int oi = cand_idx[tid][w];
                if (ov > bv || (ov == bv && oi < gi)) { bv = ov; gi = oi; }
            }
            gtop[tid][rnd] = gi;
        }
        __syncthreads();
        #pragma unroll
        for (int r = 0; r < 4; ++r) {
            const int row = quad * 4 + r;
            const int widx = gtop[row][rnd];
            if ((widx >> 8) == wave) {          // quad-uniform branch
                const int wslot = (widx >> 4) & 15;
                const int wlr = widx & 15;
                #pragma unroll
                for (int t = 0; t < 16; ++t)
                    if (wlr == lr && wslot == t) sc[t][r] = -INFINITY;
                float bv = sc[0][r]; int bs = 0;
                #pragma unroll
                for (int t = 1; t < 16; ++t)
                    if (sc[t][r] > bv) { bv = sc[t][r]; bs = t; }
                int gi = wbase + bs * 16 + lr;
                #pragma unroll
                for (int m = 1; m < 16; m <<= 1) {    // within-quad, all 16 active
                    float ov = __shfl_xor(bv, m);
                    int   oi = __shfl_xor(gi, m);
                    if (ov > bv || (ov == bv && oi < gi)) { bv = ov; gi = oi; }
                }
                if (lr == 0) { cand_val[row][wave] = bv; cand_idx[row][wave] = gi; }
            }
        }
    }
    __syncthreads();

    // ---- phase 3a: per-wave MHA; wave handles queries wave and wave+8.
    for (int qq = 0; qq < 2; ++qq) {
        const int q = wave + 8 * qq;
        const int h = lane >> 3;
        const int kk = lane & 7;
        const int i1 = gtop[q][kk], i2 = gtop[q][kk + 8];
        const _Float16* p1h = knh + (rowb + i1) * DQK + h * 16;
        const _Float16* p1l = knl + (rowb + i1) * DQK + h * 16;
        const _Float16* p2h = knh + (rowb + i2) * DQK + h * 16;
        const _Float16* p2l = knl + (rowb + i2) * DQK + h * 16;
        float lg1 = 0.f, lg2 = 0.f;
        #pragma unroll
        for (int d = 0; d < 16; ++d) {
            float qv = qs[q][h * 16 + d];
            lg1 = fmaf(qv, (float)p1h[d] + (float)p1l[d], lg1);
            lg2 = fmaf(qv, (float)p2h[d] + (float)p2l[d], lg2);
        }
        lg1 *= 0.25f; lg2 *= 0.25f;               // 1/sqrt(dh=16)
        float mx = fmaxf(lg1, lg2);
        #pragma unroll
        for (int m = 1; m < 8; m <<= 1) mx = fmaxf(mx, __shfl_xor(mx, m));
        float e1 = expf(lg1 - mx), e2 = expf(lg2 - mx);
        float ssum = e1 + e2;
        #pragma unroll
        for (int m = 1; m < 8; m <<= 1) ssum += __shfl_xor(ssum, m);
        attn_s[q][h * 16 + kk] = e1 / ssum;
        attn_s[q][h * 16 + kk + 8] = e2 / ssum;
        __syncthreads();

        float o[4] = {0.f, 0.f, 0.f, 0.f};
        for (int k = 0; k < NK; ++k) {
            const float* vr = vall + (rowb + gtop[q][k]) * DM;
            #pragma unroll
            for (int j = 0; j < 4; ++j) {
                int d = lane + 64 * j;
                o[j] = fmaf(attn_s[q][(d >> 5) * 16 + k], vr[d], o[j]);
            }
        }
        #pragma unroll
        for (int j = 0; j < 4; ++j) o16[q][lane + 64 * j] = o[j];
        __syncthreads();
    }

    // ---- phase 3b: Wo + bias + residual. 512 threads: col x query-group.
    {
        const int col = tid & 255, grp = tid >> 8;
        float acc2[8];
        #pragma unroll
        for (int q = 0; q < 8; ++q) acc2[q] = 0.f;
        for (int d = 0; d < DM; d += 4) {
            float w0 = Wo[(d + 0) * DM + col];
            float w1 = Wo[(d + 1) * DM + col];
            float w2 = Wo[(d + 2) * DM + col];
            float w3 = Wo[(d + 3) * DM + col];
            #pragma unroll
            for (int q = 0; q < 8; ++q) {
                float4 ov = *(const float4*)&o16[grp * 8 + q][d];
                acc2[q] = fmaf(ov.x, w0, acc2[q]);
                acc2[q] = fmaf(ov.y, w1, acc2[q]);
                acc2[q] = fmaf(ov.z, w2, acc2[q]);
                acc2[q] = fmaf(ov.w, w3, acc2[q]);
            }
        }
        float bov = bo[col];
        float rwv = rw[0];
        #pragma unroll
        for (int q = 0; q < 8; ++q) {
            size_t t = tq0 + grp * 8 + q;
            out[t * DM + col] = x[t * DM + col] + (acc2[q] + bov) * rwv;
        }
    }
}

// ---------------------------------------------------------------------------
// Kernel C: FFN via bf16 MFMA (unchanged R3).
// ---------------------------------------------------------------------------
__global__ __launch_bounds__(256, 2) void ffn_kernel(
    float* __restrict__ io,
    const float* __restrict__ gf, const float* __restrict__ bf,
    const unsigned short* __restrict__ W1f, const float* __restrict__ b1f,
    const unsigned short* __restrict__ W2f, const float* __restrict__ b2f,
    const float* __restrict__ rw)
{
    __shared__ __align__(16) float xs[16][260];
    __shared__ float gfs[256], bfs[256], b2s[256], b1s[1024];
    __shared__ float stat_m[16], stat_r[16];
    __shared__ __align__(16) unsigned short Af[8 * 64 * 8];
    __shared__ __align__(16) unsigned short G[16][1032];

    const int tid = threadIdx.x;
    const int lane = tid & 63, wave = tid >> 6;
    const int quad = lane >> 4, lr = lane & 15;
    const size_t t0 = (size_t)blockIdx.x * 16;

    for (int i = tid; i < 16 * 256; i += 256) xs[i >> 8][i & 255] = io[t0 * DM + i];
    gfs[tid] = gf[tid]; bfs[tid] = bf[tid]; b2s[tid] = b2f[tid];
    for (int i = tid; i < 1024; i += 256) b1s[i] = b1f[i];
    __syncthreads();

    {
        int tok = tid >> 4, l = tid & 15;
        float s = 0.f, s2 = 0.f;
        #pragma unroll
        for (int i = 0; i < 16; ++i) {
            float v = xs[tok][l + 16 * i];
            s += v; s2 += v * v;
        }
        #pragma unroll
        for (int m = 1; m < 16; m <<= 1) { s += __shfl_xor(s, m); s2 += __shfl_xor(s2, m); }
        if (l == 0) {
            float mean = s * (1.f / 256.f);
            float var  = s2 * (1.f / 256.f) - mean * mean;
            stat_m[tok] = mean;
            stat_r[tok] = rsqrtf(var + 1e-5f);
        }
    }
    __syncthreads();

    for (int kk = wave; kk < 8; kk += 4) {
        int m = lr, k0 = kk * 32 + quad * 8;
        float mm = stat_m[m], rr = stat_r[m];
        unsigned int pk[4];
        #pragma unroll
        for (int jj = 0; jj < 4; ++jj) {
            int ka = k0 + 2 * jj, kb = ka + 1;
            float v0 = (xs[m][ka] - mm) * rr * gfs[ka] + bfs[ka];
            float v1 = (xs[m][kb] - mm) * rr * gfs[kb] + bfs[kb];
            pk[jj] = (unsigned int)f2bf(v0) | ((unsigned int)f2bf(v1) << 16);
        }
        *(uint4*)&Af[(kk * 64 + lane) * 8] = make_uint4(pk[0], pk[1], pk[2], pk[3]);
    }
    __syncthreads();

    short8 afr[8];
    #pragma unroll
    for (int kk = 0; kk < 8; ++kk)
        afr[kk] = *(const short8*)&Af[(kk * 64 + lane) * 8];

    floatx4 acc[16];
    #pragma unroll
    for (int nt = 0; nt < 16; ++nt) acc[nt] = (floatx4){0.f, 0.f, 0.f, 0.f};

    const unsigned short* w1p = W1f + ((size_t)(wave * 16) * 8 * 64) * 8;
    for (int nt = 0; nt < 16; ++nt) {
        #pragma unroll
        for (int kk = 0; kk < 8; ++kk) {
            short8 bfr = *(const short8*)(w1p + (size_t)((nt * 8 + kk) * 64 + lane) * 8);
            acc[nt] = __builtin_amdgcn_mfma_f32_16x16x32_bf16(afr[kk], bfr, acc[nt], 0, 0, 0);
        }
    }

    #pragma unroll
    for (int nt = 0; nt < 16; ++nt) {
        #pragma unroll
        for (int reg = 0; reg < 4; ++reg) {
            int n = wave * 256 + nt * 16 + lr;
            int row = quad * 4 + reg;
            float h = acc[nt][reg] + b1s[n];
            G[row][n] = f2bf(gelu_fast(h));
        }
    }
    __syncthreads();

    floatx4 acc2[4];
    #pragma unroll
    for (int nt = 0; nt < 4; ++nt) acc2[nt] = (floatx4){0.f, 0.f, 0.f, 0.f};

    for (int kk2 = 0; kk2 < 32; ++kk2) {
        short8 a2 = *(const short8*)&G[lr][kk2 * 32 + quad * 8];
        #pragma unroll
        for (int nt = 0; nt < 4; ++nt) {
            short8 b2 = *(const short8*)(W2f + (size_t)(((wave * 4 + nt) * 32 + kk2) * 64 + lane) * 8);
            acc2[nt] = __builtin_amdgcn_mfma_f32_16x16x32_bf16(a2, b2, acc2[nt], 0, 0, 0);
        }
    }

    float rwv = rw[0];
    #pragma unroll
    for (int nt = 0; nt < 4; ++nt) {
        #pragma unroll
        for (int reg = 0; reg < 4; ++reg) {
            int col = wave * 64 + nt * 16 + lr;
            int row = quad * 4 + reg;
            float o = acc2[nt][reg] + b2s[col];
            io[(t0 + row) * DM + col] = xs[row][col] + o * rwv;
        }
    }
}

// ---------------------------------------------------------------------------
extern "C" void kernel_launch(void* const* d_in, const int* in_sizes, int n_in,
                              void* d_out, int out_size, void* d_ws, size_t ws_size,
                              hipStream_t stream)
{
    const float* x   = (const float*)d_in[0];
    const float* Wq  = (const float*)d_in[1];
    const float* bq  = (const float*)d_in[2];
    const float* Wk  = (const float*)d_in[3];
    const float* bk  = (const float*)d_in[4];
    const float* Wv  = (const float*)d_in[5];
    const float* bv  = (const float*)d_in[6];
    const float* Wo  = (const float*)d_in[7];
    const float* bo  = (const float*)d_in[8];
    const float* g1  = (const float*)d_in[9];
    const float* b1  = (const float*)d_in[10];
    const float* gf  = (const float*)d_in[11];
    const float* bf  = (const float*)d_in[12];
    const float* W1  = (const float*)d_in[13];
    const float* b1f = (const float*)d_in[14];
    const float* W2  = (const float*)d_in[15];
    const float* b2f = (const float*)d_in[16];
    const float* rw  = (const float*)d_in[17];
    float* out = (float*)d_out;

    // workspace (~35 MB): qn | knh | knl | vall | knsq | W1f | W2f
    float* ws = (float*)d_ws;
    float* qn = ws;                                              // 2M floats
    _Float16* knh = (_Float16*)(ws + 2097152);                   // 2M halfs = 1M floats
    _Float16* knl = (_Float16*)(ws + 3145728);                   // 2M halfs
    float* vall = ws + 4194304;                                  // 4M floats
    float* knsq = ws + 8388608;                                  // 16K floats
    unsigned short* W1f = (unsigned short*)(ws + 8404992);       // 256K shorts
    unsigned short* W2f = W1f + (size_t)DM * DFF;                // 256K shorts

    conv_kernel<<<256, 256, 0, stream>>>(W1, W2, W1f, W2f);
    proj_kernel<<<BATCH * SEQ / 8, 256, 0, stream>>>(x, Wq, bq, Wk, bk, Wv, bv, g1, b1,
                                                     qn, knh, knl, knsq, vall);
    attn_kernel<<<BATCH * SEQ / 16, 512, 0, stream>>>(x, qn, knh, knl, knsq, vall,
                                                      Wo, bo, rw, out);
    ffn_kernel<<<BATCH * SEQ / 16, 256, 0, stream>>>(out, gf, bf, W1f, b1f, W2f, b2f, rw);
}